// Round 6
// baseline (426.946 us; speedup 1.0000x reference)
//
#include <hip/hip_runtime.h>
#include <hip/hip_bf16.h>
#include <stdint.h>

#define N_EXPERTS 8
#define DIM 2048
#define INTER 1408
#define NGU (2*INTER)          // 2816
#define TOK_E 2048             // tokens per expert
#define TOTAL_TOKENS 16384

typedef __attribute__((ext_vector_type(8))) short short8;
typedef __attribute__((ext_vector_type(4))) float f32x4;

__device__ __forceinline__ unsigned short f2bf(float f) {
    union { float f; unsigned u; } v; v.f = f;
    unsigned r = v.u + 0x7FFF + ((v.u >> 16) & 1);   // RNE
    return (unsigned short)(r >> 16);
}

#define GLOAD16(G, L) __builtin_amdgcn_global_load_lds( \
    (const __attribute__((address_space(1))) void*)(G), \
    (__attribute__((address_space(3))) void*)(L), 16, 0, 0)

// ---------------- fused prep kernel ----------------
// blocks [0, 2048):              x fp32 -> bf16 (vectorized 8/lane, grid-stride)
// blocks [2048, 2048+11264):     gate_up transpose+convert+permute (128K x 32N)
// blocks [13312, 13312+5632):    down transpose+convert
#define NB_CONV 2048
#define NB_GUP  (88 * 16 * 8)    // 11264
#define NB_DWN  (64 * 11 * 8)    // 5632

__global__ __launch_bounds__(256)
void prep_fused(const float* __restrict__ x, unsigned short* __restrict__ xb,
                const float* __restrict__ gup, unsigned short* __restrict__ gub,
                const float* __restrict__ dwn, unsigned short* __restrict__ dwb) {
    __shared__ float tile[32][129];
    const int b = blockIdx.x;
    if (b < NB_CONV) {
        const int n8 = TOTAL_TOKENS * DIM / 8;
        int i = b * 256 + threadIdx.x;
        const int stride = NB_CONV * 256;
        for (; i < n8; i += stride) {
            const float4* p = (const float4*)(x + (size_t)i * 8);
            float4 v0 = p[0], v1 = p[1];
            union { unsigned short u[8]; uint4 q; } o;
            o.u[0]=f2bf(v0.x); o.u[1]=f2bf(v0.y); o.u[2]=f2bf(v0.z); o.u[3]=f2bf(v0.w);
            o.u[4]=f2bf(v1.x); o.u[5]=f2bf(v1.y); o.u[6]=f2bf(v1.z); o.u[7]=f2bf(v1.w);
            *(uint4*)(xb + (size_t)i * 8) = o.q;
        }
        return;
    }
    // transpose branches
    const float* in; unsigned short* out; int K, N, permute, local, nbx;
    if (b < NB_CONV + NB_GUP) {
        in = gup; out = gub; K = DIM; N = NGU; permute = 1;
        local = b - NB_CONV; nbx = NGU / 32;           // 88
    } else {
        in = dwn; out = dwb; K = INTER; N = DIM; permute = 0;
        local = b - NB_CONV - NB_GUP; nbx = DIM / 32;  // 64
    }
    const int bx = local % nbx;
    const int rem = local / nbx;
    const int nby = K / 128;
    const int by = rem % nby;
    const int bz = rem / nby;
    const int n0 = bx * 32, k0 = by * 128;
    const size_t ein  = (size_t)bz * K * N;
    const size_t eout = (size_t)bz * N * K;
    const int tc = threadIdx.x & 31;       // n within tile
    const int tr = threadIdx.x >> 5;       // k-row base (0..7)
    #pragma unroll
    for (int i = 0; i < 16; ++i) {
        int k = tr + i * 8;                // 0..127
        tile[tc][k] = in[ein + (size_t)(k0 + k) * N + n0 + tc];
    }
    __syncthreads();
    const int kg = threadIdx.x & 31;       // 4-element k-group (0..31)
    const int r0 = threadIdx.x >> 5;       // 0..7
    #pragma unroll
    for (int i = 0; i < 4; ++i) {
        int r = r0 + i * 8;                // output n-row 0..31
        int c = n0 + r;                    // original column
        int dr = c;
        if (permute) {                     // geglu grouping: 32-row groups {16 gate,16 up}
            int a = c >> 1;
            dr = ((a >> 4) << 5) + (a & 15) + ((c & 1) << 4);
        }
        union { unsigned short u[4]; uint2 q; } o;
        #pragma unroll
        for (int j = 0; j < 4; ++j) o.u[j] = f2bf(tile[r][kg * 4 + j]);
        *(uint2*)(out + eout + (size_t)dr * K + k0 + kg * 4) = o.q;
    }
}

// ---------------- 256x256xBK64 GEMM, 2-buffer, 8-phase half-tile pipeline ----
// (verified R4/R5: ledger, swizzle, epilogues — R6: compiler-scheduled lgkm waits,
//  no forced lgkmcnt(0) after barrier)
// LDS: sA/sB each 2 buffers x [256 rows][64 cols] bf16 (32KB/buf) = 128 KiB.
// Stage rotation: P1:b1.Ah1(kt+1) P2:b0.Ah0(kt+2) P3:b0.Bh0 P4:b0.Bh1 P5:b0.Ah1
//                 P6:b1.Ah0(kt+3) P7:b1.Bh0 P8:b1.Bh1.   vmcnt(6) @P4 and @P8.

#define SB0 __builtin_amdgcn_sched_barrier(0)
#define VMC(N_) asm volatile("s_waitcnt vmcnt(" #N_ ")" ::: "memory")

#define GEMM_PROLOG(LDKC) \
    const int t = threadIdx.x; \
    const int lane = t & 63, wid = t >> 6; \
    const int wm = wid >> 2, wn = wid & 3;            /* 2M x 4N wave grid */ \
    const int l15 = lane & 15; \
    const int rd0 = (lane & 15) * 64 + (((lane >> 4) ^ (lane & 7)) * 8); \
    const int rd1 = (lane & 15) * 64 + ((((lane >> 4) + 4) ^ (lane & 7)) * 8); \
    const size_t goff = (size_t)(t >> 3) * (LDKC) + (size_t)(((t & 7) ^ ((t >> 3) & 7)) * 8); \
    const int ldsw = wid * 512 + lane * 8;

#define STGA(LDKC, bb_, h_, kt_) do { \
    const unsigned short* g_ = gA + (size_t)(h_) * 128 * (LDKC) + (size_t)(kt_) * 64 + goff; \
    unsigned short* l_ = sA + (bb_) * 16384 + (h_) * 8192 + ldsw; \
    GLOAD16(g_, l_); GLOAD16(g_ + (size_t)64 * (LDKC), l_ + 4096); \
} while (0)

#define STGB(LDKC, bb_, h_, kt_) do { \
    const unsigned short* g_ = gB + (size_t)(h_) * 128 * (LDKC) + (size_t)(kt_) * 64 + goff; \
    unsigned short* l_ = sB + (bb_) * 16384 + (h_) * 8192 + ldsw; \
    GLOAD16(g_, l_); GLOAD16(g_ + (size_t)64 * (LDKC), l_ + 4096); \
} while (0)

#define DSA2(bb_, qm_) do { \
    const unsigned short* p_ = &sA[(bb_) * 16384 + ((qm_) * 128 + wm * 64) * 64]; \
    _Pragma("unroll") for (int m_ = 0; m_ < 4; ++m_) { \
        a[m_][0] = *(const short8*)(p_ + m_ * 1024 + rd0); \
        a[m_][1] = *(const short8*)(p_ + m_ * 1024 + rd1); } \
} while (0)

#define DSB2(bb_, qn_, R_) do { \
    const unsigned short* p_ = &sB[(bb_) * 16384 + ((qn_) * 128 + wn * 32) * 64]; \
    _Pragma("unroll") for (int n_ = 0; n_ < 2; ++n_) { \
        R_[n_][0] = *(const short8*)(p_ + n_ * 1024 + rd0); \
        R_[n_][1] = *(const short8*)(p_ + n_ * 1024 + rd1); } \
} while (0)

#define QMF(qm_, qn_, B_) do { \
    _Pragma("unroll") for (int m_ = 0; m_ < 4; ++m_) { \
        _Pragma("unroll") for (int n_ = 0; n_ < 2; ++n_) { \
            acc[qm_][qn_][m_][n_] = __builtin_amdgcn_mfma_f32_16x16x32_bf16(a[m_][0], B_[n_][0], acc[qm_][qn_][m_][n_], 0, 0, 0); \
            acc[qm_][qn_][m_][n_] = __builtin_amdgcn_mfma_f32_16x16x32_bf16(a[m_][1], B_[n_][1], acc[qm_][qn_][m_][n_], 0, 0, 0); \
        } } \
} while (0)

// R6: no forced lgkmcnt(0) — ds_reads are IR loads, compiler emits counted
// lgkm waits interleaved into the MFMA cluster. SB0 after MFMAs stops read-sink.
#define PH(DSOPS, STGOPS, MFOPS, ENDOPS) do { \
    DSOPS; \
    STGOPS; \
    SB0; \
    __builtin_amdgcn_s_barrier(); \
    __builtin_amdgcn_s_setprio(1); \
    MFOPS; \
    __builtin_amdgcn_s_setprio(0); \
    SB0; \
    ENDOPS; \
    __builtin_amdgcn_s_barrier(); \
} while (0)

#define ITER8(LDKC, kt0_, SG2, SG3, SG4, SG5, SG6, SG7, SG8, E4, E8) \
    PH(DSA2(0,0); DSB2(0,0,bq0), STGA(LDKC,1,1,(kt0_)+1), QMF(0,0,bq0), ); \
    PH(DSB2(0,1,bq1),            SG2,                     QMF(0,1,bq1), ); \
    PH(DSA2(0,1),                SG3,                     QMF(1,0,bq0), ); \
    PH(,                         SG4,                     QMF(1,1,bq1), E4); \
    PH(DSA2(1,0); DSB2(1,0,bq0), SG5,                     QMF(0,0,bq0), ); \
    PH(DSB2(1,1,bq1),            SG6,                     QMF(0,1,bq1), ); \
    PH(DSA2(1,1),                SG7,                     QMF(1,0,bq0), ); \
    PH(,                         SG8,                     QMF(1,1,bq1), E8);

#define GEMM_PIPE(LDKC, NI_) \
    short8 a[4][2], bq0[2][2], bq1[2][2]; \
    f32x4 acc[2][2][4][2]; \
    _Pragma("unroll") for (int q_ = 0; q_ < 2; ++q_) \
    _Pragma("unroll") for (int r_ = 0; r_ < 2; ++r_) \
    _Pragma("unroll") for (int m_ = 0; m_ < 4; ++m_) \
    _Pragma("unroll") for (int n_ = 0; n_ < 2; ++n_) acc[q_][r_][m_][n_] = (f32x4)0.0f; \
    /* prologue: slots P2..P8 -> b0.Ah0 b0.Bh0 b0.Bh1 b0.Ah1 b1.Ah0 b1.Bh0 b1.Bh1 */ \
    STGA(LDKC,0,0,0); STGB(LDKC,0,0,0); STGB(LDKC,0,1,0); STGA(LDKC,0,1,0); \
    STGA(LDKC,1,0,1); STGB(LDKC,1,0,1); STGB(LDKC,1,1,1); \
    VMC(6); \
    __builtin_amdgcn_s_barrier(); \
    for (int it = 0; it < (NI_) - 1; ++it) { \
        const int kt0 = 2 * it; \
        ITER8(LDKC, kt0, \
              STGA(LDKC,0,0,kt0+2), STGB(LDKC,0,0,kt0+2), STGB(LDKC,0,1,kt0+2), STGA(LDKC,0,1,kt0+2), \
              STGA(LDKC,1,0,kt0+3), STGB(LDKC,1,0,kt0+3), STGB(LDKC,1,1,kt0+3), \
              VMC(6), VMC(6)) \
    } \
    { \
        const int kt0 = 2 * ((NI_) - 1); \
        ITER8(LDKC, kt0, , , , , , , , VMC(0), ) \
    }

// ---------------- GEMM 1: x @ gate_up^T (permuted) + GEGLU, bf16 act out ----------------

__global__ __launch_bounds__(512, 2)
void gemm_gu(const unsigned short* __restrict__ A,    // x bf16 [16384][2048]
             const unsigned short* __restrict__ Bt,   // [E][2816][2048] permuted-transposed
             const float* __restrict__ probs,         // [16384]
             unsigned short* __restrict__ act) {      // [16384][1408] bf16
    __shared__ unsigned short sA[2 * 16384];
    __shared__ unsigned short sB[2 * 16384];
    GEMM_PROLOG(DIM)
    const int bid = blockIdx.x;           // 704 = 8 experts * (8 tm * 11 tn)
    const int e = bid & 7;                // expert per XCD (T1)
    const int local = bid >> 3;           // [0, 88), tm-fastest
    const int tm = local & 7;
    const int tn = local >> 3;            // [0, 11)
    const unsigned short* gA = A  + (size_t)(e * TOK_E + tm * 256) * DIM;
    const unsigned short* gB = Bt + (size_t)e * NGU * DIM + (size_t)(tn * 256) * DIM;

    GEMM_PIPE(DIM, 16)   // K = 2048 = 32 tiles of 64 = 16 iterations

    // epilogue: group g = tn*8 + qn*4 + wn; act col = g*16 + l15
    const int rgrp = lane >> 4;
    #pragma unroll
    for (int qm = 0; qm < 2; ++qm) {
        #pragma unroll
        for (int qn = 0; qn < 2; ++qn) {
            const int acol = tn * 128 + qn * 64 + wn * 16 + l15;
            #pragma unroll
            for (int m = 0; m < 4; ++m) {
                const int row0 = e * TOK_E + tm * 256 + qm * 128 + wm * 64 + m * 16 + rgrp * 4;
                #pragma unroll
                for (int j = 0; j < 4; ++j) {
                    float p = probs[row0 + j];
                    float g = fminf(acc[qm][qn][m][0][j], 7.0f);
                    float u = fminf(fmaxf(acc[qm][qn][m][1][j], -7.0f), 7.0f);
                    float glu = g / (1.0f + __expf(-1.702f * g));
                    float r = glu * (u + 1.0f) * p;
                    act[(size_t)(row0 + j) * INTER + acol] = f2bf(r);
                }
            }
        }
    }
}

// ---------------- GEMM 2: act @ down^T, fp32 out ----------------

__global__ __launch_bounds__(512, 2)
void gemm_down(const unsigned short* __restrict__ A,   // act bf16 [16384][1408]
               const unsigned short* __restrict__ Bt,  // [E][2048][1408]
               float* __restrict__ out) {               // [16384][2048] fp32
    __shared__ unsigned short sA[2 * 16384];
    __shared__ unsigned short sB[2 * 16384];
    GEMM_PROLOG(INTER)
    const int bid = blockIdx.x;           // 512 = 8 experts * (8 tm * 8 tn)
    const int e = bid & 7;
    const int local = bid >> 3;           // [0, 64), tm-fastest
    const int tm = local & 7;
    const int tn = local >> 3;            // [0, 8)
    const unsigned short* gA = A  + (size_t)(e * TOK_E + tm * 256) * INTER;
    const unsigned short* gB = Bt + (size_t)e * DIM * INTER + (size_t)(tn * 256) * INTER;

    GEMM_PIPE(INTER, 11)   // K = 1408 = 22 tiles of 64 = 11 iterations

    const int rgrp = lane >> 4;
    #pragma unroll
    for (int qm = 0; qm < 2; ++qm) {
        #pragma unroll
        for (int qn = 0; qn < 2; ++qn) {
            #pragma unroll
            for (int m = 0; m < 4; ++m) {
                const int row0 = e * TOK_E + tm * 256 + qm * 128 + wm * 64 + m * 16 + rgrp * 4;
                #pragma unroll
                for (int j = 0; j < 4; ++j) {
                    #pragma unroll
                    for (int n = 0; n < 2; ++n) {
                        const int col = tn * 256 + qn * 128 + wn * 32 + n * 16 + l15;
                        out[(size_t)(row0 + j) * DIM + col] = acc[qm][qn][m][n][j];
                    }
                }
            }
        }
    }
}

// ---------------- launcher ----------------

extern "C" void kernel_launch(void* const* d_in, const int* in_sizes, int n_in,
                              void* d_out, int out_size, void* d_ws, size_t ws_size,
                              hipStream_t stream) {
    const float* x     = (const float*)d_in[0];
    const float* probs = (const float*)d_in[1];
    const float* gup   = (const float*)d_in[2];
    const float* dwn   = (const float*)d_in[3];
    float* out = (float*)d_out;

    char* ws = (char*)d_ws;
    const size_t SZ_XB  = (size_t)TOTAL_TOKENS * DIM * 2;      // 67,108,864
    const size_t SZ_GUB = (size_t)N_EXPERTS * NGU * DIM * 2;   // 92,274,688
    const size_t SZ_DWB = (size_t)N_EXPERTS * DIM * INTER * 2; // 46,137,344
    unsigned short* xb   = (unsigned short*)(ws);
    unsigned short* gub  = (unsigned short*)(ws + SZ_XB);
    unsigned short* dwb  = (unsigned short*)(ws + SZ_XB + SZ_GUB);
    unsigned short* actb = (unsigned short*)(ws + SZ_XB + SZ_GUB + SZ_DWB);

    prep_fused<<<NB_CONV + NB_GUP + NB_DWN, 256, 0, stream>>>(x, xb, gup, gub, dwn, dwb);

    gemm_gu<<<704, 512, 0, stream>>>(xb, gub, probs, actb);
    gemm_down<<<512, 512, 0, stream>>>(actb, dwb, out);
}

// Round 7
// 410.084 us; speedup vs baseline: 1.0411x; 1.0411x over previous
//
#include <hip/hip_runtime.h>
#include <hip/hip_bf16.h>
#include <stdint.h>

#define N_EXPERTS 8
#define DIM 2048
#define INTER 1408
#define NGU (2*INTER)          // 2816
#define TOK_E 2048             // tokens per expert
#define TOTAL_TOKENS 16384

typedef __attribute__((ext_vector_type(8))) short short8;
typedef __attribute__((ext_vector_type(4))) float f32x4;

__device__ __forceinline__ unsigned short f2bf(float f) {
    union { float f; unsigned u; } v; v.f = f;
    unsigned r = v.u + 0x7FFF + ((v.u >> 16) & 1);   // RNE
    return (unsigned short)(r >> 16);
}

#define GLOAD16(G, L) __builtin_amdgcn_global_load_lds( \
    (const __attribute__((address_space(1))) void*)(G), \
    (__attribute__((address_space(3))) void*)(L), 16, 0, 0)

// ---------------- fused prep kernel (verified R6) ----------------
#define NB_CONV 2048
#define NB_GUP  (88 * 16 * 8)    // 11264
#define NB_DWN  (64 * 11 * 8)    // 5632

__global__ __launch_bounds__(256)
void prep_fused(const float* __restrict__ x, unsigned short* __restrict__ xb,
                const float* __restrict__ gup, unsigned short* __restrict__ gub,
                const float* __restrict__ dwn, unsigned short* __restrict__ dwb) {
    __shared__ float tile[32][129];
    const int b = blockIdx.x;
    if (b < NB_CONV) {
        const int n8 = TOTAL_TOKENS * DIM / 8;
        int i = b * 256 + threadIdx.x;
        const int stride = NB_CONV * 256;
        for (; i < n8; i += stride) {
            const float4* p = (const float4*)(x + (size_t)i * 8);
            float4 v0 = p[0], v1 = p[1];
            union { unsigned short u[8]; uint4 q; } o;
            o.u[0]=f2bf(v0.x); o.u[1]=f2bf(v0.y); o.u[2]=f2bf(v0.z); o.u[3]=f2bf(v0.w);
            o.u[4]=f2bf(v1.x); o.u[5]=f2bf(v1.y); o.u[6]=f2bf(v1.z); o.u[7]=f2bf(v1.w);
            *(uint4*)(xb + (size_t)i * 8) = o.q;
        }
        return;
    }
    const float* in; unsigned short* out; int K, N, permute, local, nbx;
    if (b < NB_CONV + NB_GUP) {
        in = gup; out = gub; K = DIM; N = NGU; permute = 1;
        local = b - NB_CONV; nbx = NGU / 32;           // 88
    } else {
        in = dwn; out = dwb; K = INTER; N = DIM; permute = 0;
        local = b - NB_CONV - NB_GUP; nbx = DIM / 32;  // 64
    }
    const int bx = local % nbx;
    const int rem = local / nbx;
    const int nby = K / 128;
    const int by = rem % nby;
    const int bz = rem / nby;
    const int n0 = bx * 32, k0 = by * 128;
    const size_t ein  = (size_t)bz * K * N;
    const size_t eout = (size_t)bz * N * K;
    const int tc = threadIdx.x & 31;
    const int tr = threadIdx.x >> 5;
    #pragma unroll
    for (int i = 0; i < 16; ++i) {
        int k = tr + i * 8;
        tile[tc][k] = in[ein + (size_t)(k0 + k) * N + n0 + tc];
    }
    __syncthreads();
    const int kg = threadIdx.x & 31;
    const int r0 = threadIdx.x >> 5;
    #pragma unroll
    for (int i = 0; i < 4; ++i) {
        int r = r0 + i * 8;
        int c = n0 + r;
        int dr = c;
        if (permute) {                     // geglu grouping: 32-row groups {16 gate,16 up}
            int a = c >> 1;
            dr = ((a >> 4) << 5) + (a & 15) + ((c & 1) << 4);
        }
        union { unsigned short u[4]; uint2 q; } o;
        #pragma unroll
        for (int j = 0; j < 4; ++j) o.u[j] = f2bf(tile[r][kg * 4 + j]);
        *(uint2*)(out + eout + (size_t)dr * K + k0 + kg * 4) = o.q;
    }
}

// ---------------- 256x256xBK64 GEMM, 2-buffer, 8-phase half-tile pipeline ----
// R7: ONE barrier per phase; MFMA cluster AFTER the barrier (register-only, needs
// no LDS protection). Hazard proof: write-after-read pairs (stage(p+1) vs ds(<=p))
// separated by barrier(p) since lgkm0 drains reads pre-barrier; read-after-write
// gated by vmc(6)@P4/P8 + barrier (steady-state: @P4 confirms P6,P7,P8(i-1),P1(i)
// = exactly what P5-P8 read). Waves drift <=1 phase -> ds/stage of phase p+1
// overlaps MFMA of phase p across waves.
// Stage rotation: P1:b1.Ah1(kt+1) P2:b0.Ah0(kt+2) P3:b0.Bh0 P4:b0.Bh1 P5:b0.Ah1
//                 P6:b1.Ah0(kt+3) P7:b1.Bh0 P8:b1.Bh1.   vmcnt(6) @P4 and @P8.

#define SB0 __builtin_amdgcn_sched_barrier(0)
#define VMC(N_) asm volatile("s_waitcnt vmcnt(" #N_ ")" ::: "memory")
#define LGK8 asm volatile("s_waitcnt lgkmcnt(8)" ::: "memory")

#define GEMM_PROLOG(LDKC) \
    const int t = threadIdx.x; \
    const int lane = t & 63, wid = t >> 6; \
    const int wm = wid >> 2, wn = wid & 3;            /* 2M x 4N wave grid */ \
    const int l15 = lane & 15; \
    const int rd0 = (lane & 15) * 64 + (((lane >> 4) ^ (lane & 7)) * 8); \
    const int rd1 = (lane & 15) * 64 + ((((lane >> 4) + 4) ^ (lane & 7)) * 8); \
    const size_t goff = (size_t)(t >> 3) * (LDKC) + (size_t)(((t & 7) ^ ((t >> 3) & 7)) * 8); \
    const int ldsw = wid * 512 + lane * 8;

#define STGA(LDKC, bb_, h_, kt_) do { \
    const unsigned short* g_ = gA + (size_t)(h_) * 128 * (LDKC) + (size_t)(kt_) * 64 + goff; \
    unsigned short* l_ = sA + (bb_) * 16384 + (h_) * 8192 + ldsw; \
    GLOAD16(g_, l_); GLOAD16(g_ + (size_t)64 * (LDKC), l_ + 4096); \
} while (0)

#define STGB(LDKC, bb_, h_, kt_) do { \
    const unsigned short* g_ = gB + (size_t)(h_) * 128 * (LDKC) + (size_t)(kt_) * 64 + goff; \
    unsigned short* l_ = sB + (bb_) * 16384 + (h_) * 8192 + ldsw; \
    GLOAD16(g_, l_); GLOAD16(g_ + (size_t)64 * (LDKC), l_ + 4096); \
} while (0)

#define DSA2(bb_, qm_) do { \
    const unsigned short* p_ = &sA[(bb_) * 16384 + ((qm_) * 128 + wm * 64) * 64]; \
    _Pragma("unroll") for (int m_ = 0; m_ < 4; ++m_) { \
        a[m_][0] = *(const short8*)(p_ + m_ * 1024 + rd0); \
        a[m_][1] = *(const short8*)(p_ + m_ * 1024 + rd1); } \
} while (0)

#define DSB2(bb_, qn_, R_) do { \
    const unsigned short* p_ = &sB[(bb_) * 16384 + ((qn_) * 128 + wn * 32) * 64]; \
    _Pragma("unroll") for (int n_ = 0; n_ < 2; ++n_) { \
        R_[n_][0] = *(const short8*)(p_ + n_ * 1024 + rd0); \
        R_[n_][1] = *(const short8*)(p_ + n_ * 1024 + rd1); } \
} while (0)

#define QMF(qm_, qn_, B_) do { \
    _Pragma("unroll") for (int m_ = 0; m_ < 4; ++m_) { \
        _Pragma("unroll") for (int n_ = 0; n_ < 2; ++n_) { \
            acc[qm_][qn_][m_][n_] = __builtin_amdgcn_mfma_f32_16x16x32_bf16(a[m_][0], B_[n_][0], acc[qm_][qn_][m_][n_], 0, 0, 0); \
            acc[qm_][qn_][m_][n_] = __builtin_amdgcn_mfma_f32_16x16x32_bf16(a[m_][1], B_[n_][1], acc[qm_][qn_][m_][n_], 0, 0, 0); \
        } } \
} while (0)

// one barrier per phase; lgkm0 + vmc (ENDOPS) BEFORE it; MFMA after it.
#define PH(DSOPS, STGOPS, MFOPS, ENDOPS) do { \
    DSOPS; \
    STGOPS; \
    SB0; \
    asm volatile("s_waitcnt lgkmcnt(0)" ::: "memory"); \
    ENDOPS; \
    SB0; \
    __builtin_amdgcn_s_barrier(); \
    __builtin_amdgcn_s_setprio(1); \
    MFOPS; \
    __builtin_amdgcn_s_setprio(0); \
    SB0; \
} while (0)

#define ITER8(LDKC, kt0_, SG2, SG3, SG4, SG5, SG6, SG7, SG8, E4, E8) \
    PH(DSA2(0,0); DSB2(0,0,bq0); LGK8, STGA(LDKC,1,1,(kt0_)+1), QMF(0,0,bq0), ); \
    PH(DSB2(0,1,bq1),            SG2,                     QMF(0,1,bq1), ); \
    PH(DSA2(0,1),                SG3,                     QMF(1,0,bq0), ); \
    PH(,                         SG4,                     QMF(1,1,bq1), E4); \
    PH(DSA2(1,0); DSB2(1,0,bq0); LGK8, SG5,               QMF(0,0,bq0), ); \
    PH(DSB2(1,1,bq1),            SG6,                     QMF(0,1,bq1), ); \
    PH(DSA2(1,1),                SG7,                     QMF(1,0,bq0), ); \
    PH(,                         SG8,                     QMF(1,1,bq1), E8);

#define GEMM_PIPE(LDKC, NI_) \
    short8 a[4][2], bq0[2][2], bq1[2][2]; \
    f32x4 acc[2][2][4][2]; \
    _Pragma("unroll") for (int q_ = 0; q_ < 2; ++q_) \
    _Pragma("unroll") for (int r_ = 0; r_ < 2; ++r_) \
    _Pragma("unroll") for (int m_ = 0; m_ < 4; ++m_) \
    _Pragma("unroll") for (int n_ = 0; n_ < 2; ++n_) acc[q_][r_][m_][n_] = (f32x4)0.0f; \
    /* prologue: slots P2..P8 -> b0.Ah0 b0.Bh0 b0.Bh1 b0.Ah1 b1.Ah0 b1.Bh0 b1.Bh1 */ \
    STGA(LDKC,0,0,0); STGB(LDKC,0,0,0); STGB(LDKC,0,1,0); STGA(LDKC,0,1,0); \
    STGA(LDKC,1,0,1); STGB(LDKC,1,0,1); STGB(LDKC,1,1,1); \
    VMC(6); \
    __builtin_amdgcn_s_barrier(); \
    for (int it = 0; it < (NI_) - 1; ++it) { \
        const int kt0 = 2 * it; \
        ITER8(LDKC, kt0, \
              STGA(LDKC,0,0,kt0+2), STGB(LDKC,0,0,kt0+2), STGB(LDKC,0,1,kt0+2), STGA(LDKC,0,1,kt0+2), \
              STGA(LDKC,1,0,kt0+3), STGB(LDKC,1,0,kt0+3), STGB(LDKC,1,1,kt0+3), \
              VMC(6), VMC(6)) \
    } \
    { \
        const int kt0 = 2 * ((NI_) - 1); \
        ITER8(LDKC, kt0, , , , , , , , VMC(0), ) \
    }

// ---------------- GEMM 1: x @ gate_up^T (permuted) + GEGLU, bf16 act out ----------------

__global__ __launch_bounds__(512, 2)
void gemm_gu(const unsigned short* __restrict__ A,    // x bf16 [16384][2048]
             const unsigned short* __restrict__ Bt,   // [E][2816][2048] permuted-transposed
             const float* __restrict__ probs,         // [16384]
             unsigned short* __restrict__ act) {      // [16384][1408] bf16
    __shared__ unsigned short sA[2 * 16384];
    __shared__ unsigned short sB[2 * 16384];
    GEMM_PROLOG(DIM)
    const int bid = blockIdx.x;           // 704 = 8 experts * (8 tm * 11 tn)
    const int e = bid & 7;                // expert per XCD (T1)
    const int local = bid >> 3;           // [0, 88), tm-fastest
    const int tm = local & 7;
    const int tn = local >> 3;            // [0, 11)
    const unsigned short* gA = A  + (size_t)(e * TOK_E + tm * 256) * DIM;
    const unsigned short* gB = Bt + (size_t)e * NGU * DIM + (size_t)(tn * 256) * DIM;

    GEMM_PIPE(DIM, 16)   // K = 2048 = 32 tiles of 64 = 16 iterations

    // epilogue: group g = tn*8 + qn*4 + wn; act col = g*16 + l15
    const int rgrp = lane >> 4;
    #pragma unroll
    for (int qm = 0; qm < 2; ++qm) {
        #pragma unroll
        for (int qn = 0; qn < 2; ++qn) {
            const int acol = tn * 128 + qn * 64 + wn * 16 + l15;
            #pragma unroll
            for (int m = 0; m < 4; ++m) {
                const int row0 = e * TOK_E + tm * 256 + qm * 128 + wm * 64 + m * 16 + rgrp * 4;
                #pragma unroll
                for (int j = 0; j < 4; ++j) {
                    float p = probs[row0 + j];
                    float g = fminf(acc[qm][qn][m][0][j], 7.0f);
                    float u = fminf(fmaxf(acc[qm][qn][m][1][j], -7.0f), 7.0f);
                    float glu = g / (1.0f + __expf(-1.702f * g));
                    float r = glu * (u + 1.0f) * p;
                    act[(size_t)(row0 + j) * INTER + acol] = f2bf(r);
                }
            }
        }
    }
}

// ---------------- GEMM 2: act @ down^T, fp32 out ----------------

__global__ __launch_bounds__(512, 2)
void gemm_down(const unsigned short* __restrict__ A,   // act bf16 [16384][1408]
               const unsigned short* __restrict__ Bt,  // [E][2048][1408]
               float* __restrict__ out) {               // [16384][2048] fp32
    __shared__ unsigned short sA[2 * 16384];
    __shared__ unsigned short sB[2 * 16384];
    GEMM_PROLOG(INTER)
    const int bid = blockIdx.x;           // 512 = 8 experts * (8 tm * 8 tn)
    const int e = bid & 7;
    const int local = bid >> 3;           // [0, 64), tm-fastest
    const int tm = local & 7;
    const int tn = local >> 3;            // [0, 8)
    const unsigned short* gA = A  + (size_t)(e * TOK_E + tm * 256) * INTER;
    const unsigned short* gB = Bt + (size_t)e * DIM * INTER + (size_t)(tn * 256) * INTER;

    GEMM_PIPE(INTER, 11)   // K = 1408 = 22 tiles of 64 = 11 iterations

    const int rgrp = lane >> 4;
    #pragma unroll
    for (int qm = 0; qm < 2; ++qm) {
        #pragma unroll
        for (int qn = 0; qn < 2; ++qn) {
            #pragma unroll
            for (int m = 0; m < 4; ++m) {
                const int row0 = e * TOK_E + tm * 256 + qm * 128 + wm * 64 + m * 16 + rgrp * 4;
                #pragma unroll
                for (int j = 0; j < 4; ++j) {
                    #pragma unroll
                    for (int n = 0; n < 2; ++n) {
                        const int col = tn * 256 + qn * 128 + wn * 32 + n * 16 + l15;
                        out[(size_t)(row0 + j) * DIM + col] = acc[qm][qn][m][n][j];
                    }
                }
            }
        }
    }
}

// ---------------- launcher ----------------

extern "C" void kernel_launch(void* const* d_in, const int* in_sizes, int n_in,
                              void* d_out, int out_size, void* d_ws, size_t ws_size,
                              hipStream_t stream) {
    const float* x     = (const float*)d_in[0];
    const float* probs = (const float*)d_in[1];
    const float* gup   = (const float*)d_in[2];
    const float* dwn   = (const float*)d_in[3];
    float* out = (float*)d_out;

    char* ws = (char*)d_ws;
    const size_t SZ_XB  = (size_t)TOTAL_TOKENS * DIM * 2;      // 67,108,864
    const size_t SZ_GUB = (size_t)N_EXPERTS * NGU * DIM * 2;   // 92,274,688
    const size_t SZ_DWB = (size_t)N_EXPERTS * DIM * INTER * 2; // 46,137,344
    unsigned short* xb   = (unsigned short*)(ws);
    unsigned short* gub  = (unsigned short*)(ws + SZ_XB);
    unsigned short* dwb  = (unsigned short*)(ws + SZ_XB + SZ_GUB);
    unsigned short* actb = (unsigned short*)(ws + SZ_XB + SZ_GUB + SZ_DWB);

    prep_fused<<<NB_CONV + NB_GUP + NB_DWN, 256, 0, stream>>>(x, xb, gup, gub, dwn, dwb);

    gemm_gu<<<704, 512, 0, stream>>>(xb, gub, probs, actb);
    gemm_down<<<512, 512, 0, stream>>>(actb, dwb, out);
}

// Round 9
// 404.812 us; speedup vs baseline: 1.0547x; 1.0130x over previous
//
#include <hip/hip_runtime.h>
#include <hip/hip_bf16.h>
#include <stdint.h>

#define N_EXPERTS 8
#define DIM 2048
#define INTER 1408
#define NGU (2*INTER)          // 2816
#define TOK_E 2048             // tokens per expert
#define TOTAL_TOKENS 16384

typedef __attribute__((ext_vector_type(8))) short short8;
typedef __attribute__((ext_vector_type(4))) float f32x4;

__device__ __forceinline__ unsigned short f2bf(float f) {
    union { float f; unsigned u; } v; v.f = f;
    unsigned r = v.u + 0x7FFF + ((v.u >> 16) & 1);   // RNE
    return (unsigned short)(r >> 16);
}

#define GLOAD16(G, L) __builtin_amdgcn_global_load_lds( \
    (const __attribute__((address_space(1))) void*)(G), \
    (__attribute__((address_space(3))) void*)(L), 16, 0, 0)

// ---------------- prep kernels (R5 form, verified) ----------------

__global__ void convert_x(const float* __restrict__ in, unsigned short* __restrict__ out, int n8) {
    int i = blockIdx.x * blockDim.x + threadIdx.x;
    int stride = gridDim.x * blockDim.x;
    for (; i < n8; i += stride) {
        const float4* p = (const float4*)(in + (size_t)i * 8);
        float4 v0 = p[0], v1 = p[1];
        union { unsigned short u[8]; uint4 q; } o;
        o.u[0]=f2bf(v0.x); o.u[1]=f2bf(v0.y); o.u[2]=f2bf(v0.z); o.u[3]=f2bf(v0.w);
        o.u[4]=f2bf(v1.x); o.u[5]=f2bf(v1.y); o.u[6]=f2bf(v1.z); o.u[7]=f2bf(v1.w);
        *(uint4*)(out + (size_t)i * 8) = o.q;
    }
}

// in: [E][K][N] fp32 -> out: [E][N][K] bf16, 128(K)x32(N) per block, 8B stores.
__global__ __launch_bounds__(256)
void transpose_convert(const float* __restrict__ in, unsigned short* __restrict__ out,
                       int K, int N, int permute) {
    __shared__ float tile[32][129];
    const int n0 = blockIdx.x * 32, k0 = blockIdx.y * 128;
    const size_t ein  = (size_t)blockIdx.z * K * N;
    const size_t eout = (size_t)blockIdx.z * N * K;
    const int tc = threadIdx.x & 31;
    const int tr = threadIdx.x >> 5;
    #pragma unroll
    for (int i = 0; i < 16; ++i) {
        int k = tr + i * 8;
        tile[tc][k] = in[ein + (size_t)(k0 + k) * N + n0 + tc];
    }
    __syncthreads();
    const int kg = threadIdx.x & 31;
    const int r0 = threadIdx.x >> 5;
    #pragma unroll
    for (int i = 0; i < 4; ++i) {
        int r = r0 + i * 8;
        int c = n0 + r;
        int dr = c;
        if (permute) {                     // geglu grouping: 32-row groups {16 gate,16 up}
            int a = c >> 1;
            dr = ((a >> 4) << 5) + (a & 15) + ((c & 1) << 4);
        }
        union { unsigned short u[4]; uint2 q; } o;
        #pragma unroll
        for (int j = 0; j < 4; ++j) o.u[j] = f2bf(tile[r][kg * 4 + j]);
        *(uint2*)(out + eout + (size_t)dr * K + k0 + kg * 4) = o.q;
    }
}

// ---------------- 256x256xBK64 GEMM, 2-buffer, 8-phase pipeline (R9) ---------
// R7 skeleton (verified): window = DS;STG;SB0;WAIT;END;SB0;barrier;prio;MFMA;prio;SB0.
// R9 delta: deferred-B read schedule. P1/P5 read c0(Bh0)+a(Ah0)+c1(Bh1) [16];
// P3/P7 read a(Ah1) [8]; P2/P4/P6/P8 read nothing (c0/c1 held in regs).
// WAIT: P1/P5 = lgkmcnt(4) (drains c0+a strictly; c1 flies, lands under next
// window's MFMA, 3 windows before its P4/P8 overwrite); P3/P7 = lgkmcnt(0).
// Stage rotation & VMC(6)@P4/P8 identical to R4-R7 (hardware-verified ledger):
// P1:b1.Ah1(kt+1) P2:b0.Ah0(kt+2) P3:b0.Bh0 P4:b0.Bh1 P5:b0.Ah1
// P6:b1.Ah0(kt+3) P7:b1.Bh0 P8:b1.Bh1.
// Registers: a(32)+c0(16)+c1(16) VGPR = R7's exact budget -> no spills (R8's
// failure: +48 VGPR double-buffer spilled; scratch VMEM corrupted the vmcnt ledger).

#define SB0 __builtin_amdgcn_sched_barrier(0)
#define VMC(N_) asm volatile("s_waitcnt vmcnt(" #N_ ")" ::: "memory")
#define LGKM(N_) asm volatile("s_waitcnt lgkmcnt(" #N_ ")" ::: "memory")

#define GEMM_PROLOG(LDKC) \
    const int t = threadIdx.x; \
    const int lane = t & 63, wid = t >> 6; \
    const int wm = wid >> 2, wn = wid & 3;            /* 2M x 4N wave grid */ \
    const int l15 = lane & 15; \
    const int rd0 = (lane & 15) * 64 + (((lane >> 4) ^ (lane & 7)) * 8); \
    const int rd1 = (lane & 15) * 64 + ((((lane >> 4) + 4) ^ (lane & 7)) * 8); \
    const size_t goff = (size_t)(t >> 3) * (LDKC) + (size_t)(((t & 7) ^ ((t >> 3) & 7)) * 8); \
    const int ldsw = wid * 512 + lane * 8;

#define STGA(LDKC, bb_, h_, kt_) do { \
    const unsigned short* g_ = gA + (size_t)(h_) * 128 * (LDKC) + (size_t)(kt_) * 64 + goff; \
    unsigned short* l_ = sA + (bb_) * 16384 + (h_) * 8192 + ldsw; \
    GLOAD16(g_, l_); GLOAD16(g_ + (size_t)64 * (LDKC), l_ + 4096); \
} while (0)

#define STGB(LDKC, bb_, h_, kt_) do { \
    const unsigned short* g_ = gB + (size_t)(h_) * 128 * (LDKC) + (size_t)(kt_) * 64 + goff; \
    unsigned short* l_ = sB + (bb_) * 16384 + (h_) * 8192 + ldsw; \
    GLOAD16(g_, l_); GLOAD16(g_ + (size_t)64 * (LDKC), l_ + 4096); \
} while (0)

#define DSA2(bb_, qm_) do { \
    const unsigned short* p_ = &sA[(bb_) * 16384 + ((qm_) * 128 + wm * 64) * 64]; \
    _Pragma("unroll") for (int m_ = 0; m_ < 4; ++m_) { \
        a[m_][0] = *(const short8*)(p_ + m_ * 1024 + rd0); \
        a[m_][1] = *(const short8*)(p_ + m_ * 1024 + rd1); } \
} while (0)

#define DSB2(bb_, qn_, R_) do { \
    const unsigned short* p_ = &sB[(bb_) * 16384 + ((qn_) * 128 + wn * 32) * 64]; \
    _Pragma("unroll") for (int n_ = 0; n_ < 2; ++n_) { \
        R_[n_][0] = *(const short8*)(p_ + n_ * 1024 + rd0); \
        R_[n_][1] = *(const short8*)(p_ + n_ * 1024 + rd1); } \
} while (0)

#define QMF(qm_, qn_, B_) do { \
    _Pragma("unroll") for (int m_ = 0; m_ < 4; ++m_) { \
        _Pragma("unroll") for (int n_ = 0; n_ < 2; ++n_) { \
            acc[qm_][qn_][m_][n_] = __builtin_amdgcn_mfma_f32_16x16x32_bf16(a[m_][0], B_[n_][0], acc[qm_][qn_][m_][n_], 0, 0, 0); \
            acc[qm_][qn_][m_][n_] = __builtin_amdgcn_mfma_f32_16x16x32_bf16(a[m_][1], B_[n_][1], acc[qm_][qn_][m_][n_], 0, 0, 0); \
        } } \
} while (0)

// R7 window skeleton; WAITOP is counted (or empty) per the R9 read schedule.
#define PH(DSOPS, STGOPS, WAITOP, ENDOPS, MFOPS) do { \
    DSOPS; \
    STGOPS; \
    SB0; \
    WAITOP; \
    ENDOPS; \
    SB0; \
    __builtin_amdgcn_s_barrier(); \
    __builtin_amdgcn_s_setprio(1); \
    MFOPS; \
    __builtin_amdgcn_s_setprio(0); \
    SB0; \
} while (0)

#define ITER8(LDKC, kt0_, SG2, SG3, SG4, SG5, SG6, SG7, SG8, E4, E8) \
    PH(DSB2(0,0,c0); DSA2(0,0); DSB2(0,1,c1), STGA(LDKC,1,1,(kt0_)+1), LGKM(4), , QMF(0,0,c0)); \
    PH(,                                      SG2,                     ,       , QMF(0,1,c1)); \
    PH(DSA2(0,1),                             SG3,                     LGKM(0), , QMF(1,0,c0)); \
    PH(,                                      SG4,                     ,     E4, QMF(1,1,c1)); \
    PH(DSB2(1,0,c0); DSA2(1,0); DSB2(1,1,c1), SG5,                     LGKM(4), , QMF(0,0,c0)); \
    PH(,                                      SG6,                     ,       , QMF(0,1,c1)); \
    PH(DSA2(1,1),                             SG7,                     LGKM(0), , QMF(1,0,c0)); \
    PH(,                                      SG8,                     ,     E8, QMF(1,1,c1));

#define GEMM_PIPE(LDKC, NI_) \
    short8 a[4][2], c0[2][2], c1[2][2]; \
    f32x4 acc[2][2][4][2]; \
    _Pragma("unroll") for (int q_ = 0; q_ < 2; ++q_) \
    _Pragma("unroll") for (int r_ = 0; r_ < 2; ++r_) \
    _Pragma("unroll") for (int m_ = 0; m_ < 4; ++m_) \
    _Pragma("unroll") for (int n_ = 0; n_ < 2; ++n_) acc[q_][r_][m_][n_] = (f32x4)0.0f; \
    /* prologue: slots P2..P8 -> b0.Ah0 b0.Bh0 b0.Bh1 b0.Ah1 b1.Ah0 b1.Bh0 b1.Bh1 */ \
    STGA(LDKC,0,0,0); STGB(LDKC,0,0,0); STGB(LDKC,0,1,0); STGA(LDKC,0,1,0); \
    STGA(LDKC,1,0,1); STGB(LDKC,1,0,1); STGB(LDKC,1,1,1); \
    VMC(6); \
    __builtin_amdgcn_s_barrier(); \
    for (int it = 0; it < (NI_) - 1; ++it) { \
        const int kt0 = 2 * it; \
        ITER8(LDKC, kt0, \
              STGA(LDKC,0,0,kt0+2), STGB(LDKC,0,0,kt0+2), STGB(LDKC,0,1,kt0+2), STGA(LDKC,0,1,kt0+2), \
              STGA(LDKC,1,0,kt0+3), STGB(LDKC,1,0,kt0+3), STGB(LDKC,1,1,kt0+3), \
              VMC(6), VMC(6)) \
    } \
    { \
        const int kt0 = 2 * ((NI_) - 1); \
        ITER8(LDKC, kt0, , , , , , , , VMC(0), ) \
    }

// ---------------- GEMM 1: x @ gate_up^T (permuted) + GEGLU, bf16 act out ----------------

__global__ __launch_bounds__(512, 2)
void gemm_gu(const unsigned short* __restrict__ A,    // x bf16 [16384][2048]
             const unsigned short* __restrict__ Bt,   // [E][2816][2048] permuted-transposed
             const float* __restrict__ probs,         // [16384]
             unsigned short* __restrict__ act) {      // [16384][1408] bf16
    __shared__ unsigned short sA[2 * 16384];
    __shared__ unsigned short sB[2 * 16384];
    GEMM_PROLOG(DIM)
    const int bid = blockIdx.x;           // 704 = 8 experts * (8 tm * 11 tn)
    const int e = bid & 7;                // expert per XCD (T1)
    const int local = bid >> 3;           // [0, 88), tm-fastest
    const int tm = local & 7;
    const int tn = local >> 3;            // [0, 11)
    const unsigned short* gA = A  + (size_t)(e * TOK_E + tm * 256) * DIM;
    const unsigned short* gB = Bt + (size_t)e * NGU * DIM + (size_t)(tn * 256) * DIM;

    GEMM_PIPE(DIM, 16)   // K = 2048 = 32 tiles of 64 = 16 iterations

    // epilogue: group g = tn*8 + qn*4 + wn; act col = g*16 + l15
    const int rgrp = lane >> 4;
    #pragma unroll
    for (int qm = 0; qm < 2; ++qm) {
        #pragma unroll
        for (int qn = 0; qn < 2; ++qn) {
            const int acol = tn * 128 + qn * 64 + wn * 16 + l15;
            #pragma unroll
            for (int m = 0; m < 4; ++m) {
                const int row0 = e * TOK_E + tm * 256 + qm * 128 + wm * 64 + m * 16 + rgrp * 4;
                #pragma unroll
                for (int j = 0; j < 4; ++j) {
                    float p = probs[row0 + j];
                    float g = fminf(acc[qm][qn][m][0][j], 7.0f);
                    float u = fminf(fmaxf(acc[qm][qn][m][1][j], -7.0f), 7.0f);
                    float glu = g / (1.0f + __expf(-1.702f * g));
                    float r = glu * (u + 1.0f) * p;
                    act[(size_t)(row0 + j) * INTER + acol] = f2bf(r);
                }
            }
        }
    }
}

// ---------------- GEMM 2: act @ down^T, fp32 out ----------------

__global__ __launch_bounds__(512, 2)
void gemm_down(const unsigned short* __restrict__ A,   // act bf16 [16384][1408]
               const unsigned short* __restrict__ Bt,  // [E][2048][1408]
               float* __restrict__ out) {               // [16384][2048] fp32
    __shared__ unsigned short sA[2 * 16384];
    __shared__ unsigned short sB[2 * 16384];
    GEMM_PROLOG(INTER)
    const int bid = blockIdx.x;           // 512 = 8 experts * (8 tm * 8 tn)
    const int e = bid & 7;
    const int local = bid >> 3;           // [0, 64), tm-fastest
    const int tm = local & 7;
    const int tn = local >> 3;            // [0, 8)
    const unsigned short* gA = A  + (size_t)(e * TOK_E + tm * 256) * INTER;
    const unsigned short* gB = Bt + (size_t)e * DIM * INTER + (size_t)(tn * 256) * INTER;

    GEMM_PIPE(INTER, 11)   // K = 1408 = 22 tiles of 64 = 11 iterations

    const int rgrp = lane >> 4;
    #pragma unroll
    for (int qm = 0; qm < 2; ++qm) {
        #pragma unroll
        for (int qn = 0; qn < 2; ++qn) {
            #pragma unroll
            for (int m = 0; m < 4; ++m) {
                const int row0 = e * TOK_E + tm * 256 + qm * 128 + wm * 64 + m * 16 + rgrp * 4;
                #pragma unroll
                for (int j = 0; j < 4; ++j) {
                    #pragma unroll
                    for (int n = 0; n < 2; ++n) {
                        const int col = tn * 256 + qn * 128 + wn * 32 + n * 16 + l15;
                        out[(size_t)(row0 + j) * DIM + col] = acc[qm][qn][m][n][j];
                    }
                }
            }
        }
    }
}

// ---------------- launcher ----------------

extern "C" void kernel_launch(void* const* d_in, const int* in_sizes, int n_in,
                              void* d_out, int out_size, void* d_ws, size_t ws_size,
                              hipStream_t stream) {
    const float* x     = (const float*)d_in[0];
    const float* probs = (const float*)d_in[1];
    const float* gup   = (const float*)d_in[2];
    const float* dwn   = (const float*)d_in[3];
    float* out = (float*)d_out;

    char* ws = (char*)d_ws;
    const size_t SZ_XB  = (size_t)TOTAL_TOKENS * DIM * 2;      // 67,108,864
    const size_t SZ_GUB = (size_t)N_EXPERTS * NGU * DIM * 2;   // 92,274,688
    const size_t SZ_DWB = (size_t)N_EXPERTS * DIM * INTER * 2; // 46,137,344
    unsigned short* xb   = (unsigned short*)(ws);
    unsigned short* gub  = (unsigned short*)(ws + SZ_XB);
    unsigned short* dwb  = (unsigned short*)(ws + SZ_XB + SZ_GUB);
    unsigned short* actb = (unsigned short*)(ws + SZ_XB + SZ_GUB + SZ_DWB);

    convert_x<<<2048, 256, 0, stream>>>(x, xb, TOTAL_TOKENS * DIM / 8);

    dim3 tg1(NGU / 32, DIM / 128, N_EXPERTS);     // (88, 16, 8)
    transpose_convert<<<tg1, 256, 0, stream>>>(gup, gub, DIM, NGU, 1);
    dim3 tg2(DIM / 32, INTER / 128, N_EXPERTS);   // (64, 11, 8)
    transpose_convert<<<tg2, 256, 0, stream>>>(dwn, dwb, INTER, DIM, 0);

    gemm_gu<<<704, 512, 0, stream>>>(xb, gub, probs, actb);
    gemm_down<<<512, 512, 0, stream>>>(actb, dwb, out);
}

// Round 10
// 400.234 us; speedup vs baseline: 1.0667x; 1.0114x over previous
//
#include <hip/hip_runtime.h>
#include <hip/hip_bf16.h>
#include <stdint.h>

#define N_EXPERTS 8
#define DIM 2048
#define INTER 1408
#define NGU (2*INTER)          // 2816
#define TOK_E 2048             // tokens per expert
#define TOTAL_TOKENS 16384

typedef __attribute__((ext_vector_type(8))) short short8;
typedef __attribute__((ext_vector_type(4))) float f32x4;

__device__ __forceinline__ unsigned short f2bf(float f) {
    union { float f; unsigned u; } v; v.f = f;
    unsigned r = v.u + 0x7FFF + ((v.u >> 16) & 1);   // RNE
    return (unsigned short)(r >> 16);
}

#define GLOAD16(G, L) __builtin_amdgcn_global_load_lds( \
    (const __attribute__((address_space(1))) void*)(G), \
    (__attribute__((address_space(3))) void*)(L), 16, 0, 0)

// ---------------- prep kernels (R5/R9 form, verified) ----------------

__global__ void convert_x(const float* __restrict__ in, unsigned short* __restrict__ out, int n8) {
    int i = blockIdx.x * blockDim.x + threadIdx.x;
    int stride = gridDim.x * blockDim.x;
    for (; i < n8; i += stride) {
        const float4* p = (const float4*)(in + (size_t)i * 8);
        float4 v0 = p[0], v1 = p[1];
        union { unsigned short u[8]; uint4 q; } o;
        o.u[0]=f2bf(v0.x); o.u[1]=f2bf(v0.y); o.u[2]=f2bf(v0.z); o.u[3]=f2bf(v0.w);
        o.u[4]=f2bf(v1.x); o.u[5]=f2bf(v1.y); o.u[6]=f2bf(v1.z); o.u[7]=f2bf(v1.w);
        *(uint4*)(out + (size_t)i * 8) = o.q;
    }
}

// in: [E][K][N] fp32 -> out: [E][N][K] bf16, 128(K)x32(N) per block, 8B stores.
__global__ __launch_bounds__(256)
void transpose_convert(const float* __restrict__ in, unsigned short* __restrict__ out,
                       int K, int N, int permute) {
    __shared__ float tile[32][129];
    const int n0 = blockIdx.x * 32, k0 = blockIdx.y * 128;
    const size_t ein  = (size_t)blockIdx.z * K * N;
    const size_t eout = (size_t)blockIdx.z * N * K;
    const int tc = threadIdx.x & 31;
    const int tr = threadIdx.x >> 5;
    #pragma unroll
    for (int i = 0; i < 16; ++i) {
        int k = tr + i * 8;
        tile[tc][k] = in[ein + (size_t)(k0 + k) * N + n0 + tc];
    }
    __syncthreads();
    const int kg = threadIdx.x & 31;
    const int r0 = threadIdx.x >> 5;
    #pragma unroll
    for (int i = 0; i < 4; ++i) {
        int r = r0 + i * 8;
        int c = n0 + r;
        int dr = c;
        if (permute) {                     // geglu grouping: 32-row groups {16 gate,16 up}
            int a = c >> 1;
            dr = ((a >> 4) << 5) + (a & 15) + ((c & 1) << 4);
        }
        union { unsigned short u[4]; uint2 q; } o;
        #pragma unroll
        for (int j = 0; j < 4; ++j) o.u[j] = f2bf(tile[r][kg * 4 + j]);
        *(uint2*)(out + eout + (size_t)dr * K + k0 + kg * 4) = o.q;
    }
}

// ---------------- 256x256xBK64 GEMM, 2-buffer, 8-phase pipeline (R10) --------
// R7 skeleton (best measured: 189.9us, 43.1% MfmaUtil), byte-identical except
// QMF is k-OUTER: the two k-half MFMAs writing the same acc are separated by 7
// independent MFMAs (breaks back-to-back dependent-MFMA latency stalls).
// Window: DS;STG;SB0;lgkm0;END;SB0;barrier;setprio;MFMA;setprio;SB0.
// Stage rotation: P1:b1.Ah1(kt+1) P2:b0.Ah0(kt+2) P3:b0.Bh0 P4:b0.Bh1 P5:b0.Ah1
//                 P6:b1.Ah0(kt+3) P7:b1.Bh0 P8:b1.Bh1.   vmcnt(6) @P4 and @P8.

#define SB0 __builtin_amdgcn_sched_barrier(0)
#define VMC(N_) asm volatile("s_waitcnt vmcnt(" #N_ ")" ::: "memory")
#define LGK8 asm volatile("s_waitcnt lgkmcnt(8)" ::: "memory")

#define GEMM_PROLOG(LDKC) \
    const int t = threadIdx.x; \
    const int lane = t & 63, wid = t >> 6; \
    const int wm = wid >> 2, wn = wid & 3;            /* 2M x 4N wave grid */ \
    const int l15 = lane & 15; \
    const int rd0 = (lane & 15) * 64 + (((lane >> 4) ^ (lane & 7)) * 8); \
    const int rd1 = (lane & 15) * 64 + ((((lane >> 4) + 4) ^ (lane & 7)) * 8); \
    const size_t goff = (size_t)(t >> 3) * (LDKC) + (size_t)(((t & 7) ^ ((t >> 3) & 7)) * 8); \
    const int ldsw = wid * 512 + lane * 8;

#define STGA(LDKC, bb_, h_, kt_) do { \
    const unsigned short* g_ = gA + (size_t)(h_) * 128 * (LDKC) + (size_t)(kt_) * 64 + goff; \
    unsigned short* l_ = sA + (bb_) * 16384 + (h_) * 8192 + ldsw; \
    GLOAD16(g_, l_); GLOAD16(g_ + (size_t)64 * (LDKC), l_ + 4096); \
} while (0)

#define STGB(LDKC, bb_, h_, kt_) do { \
    const unsigned short* g_ = gB + (size_t)(h_) * 128 * (LDKC) + (size_t)(kt_) * 64 + goff; \
    unsigned short* l_ = sB + (bb_) * 16384 + (h_) * 8192 + ldsw; \
    GLOAD16(g_, l_); GLOAD16(g_ + (size_t)64 * (LDKC), l_ + 4096); \
} while (0)

#define DSA2(bb_, qm_) do { \
    const unsigned short* p_ = &sA[(bb_) * 16384 + ((qm_) * 128 + wm * 64) * 64]; \
    _Pragma("unroll") for (int m_ = 0; m_ < 4; ++m_) { \
        a[m_][0] = *(const short8*)(p_ + m_ * 1024 + rd0); \
        a[m_][1] = *(const short8*)(p_ + m_ * 1024 + rd1); } \
} while (0)

#define DSB2(bb_, qn_, R_) do { \
    const unsigned short* p_ = &sB[(bb_) * 16384 + ((qn_) * 128 + wn * 32) * 64]; \
    _Pragma("unroll") for (int n_ = 0; n_ < 2; ++n_) { \
        R_[n_][0] = *(const short8*)(p_ + n_ * 1024 + rd0); \
        R_[n_][1] = *(const short8*)(p_ + n_ * 1024 + rd1); } \
} while (0)

// R10: k-outer — 8 independent MFMAs between the two writes of any acc reg.
#define QMF(qm_, qn_, B_) do { \
    _Pragma("unroll") for (int k_ = 0; k_ < 2; ++k_) { \
        _Pragma("unroll") for (int m_ = 0; m_ < 4; ++m_) { \
            _Pragma("unroll") for (int n_ = 0; n_ < 2; ++n_) { \
                acc[qm_][qn_][m_][n_] = __builtin_amdgcn_mfma_f32_16x16x32_bf16(a[m_][k_], B_[n_][k_], acc[qm_][qn_][m_][n_], 0, 0, 0); \
            } } } \
} while (0)

// one barrier per phase; lgkm0 + vmc (ENDOPS) BEFORE it; MFMA after it.
#define PH(DSOPS, STGOPS, MFOPS, ENDOPS) do { \
    DSOPS; \
    STGOPS; \
    SB0; \
    asm volatile("s_waitcnt lgkmcnt(0)" ::: "memory"); \
    ENDOPS; \
    SB0; \
    __builtin_amdgcn_s_barrier(); \
    __builtin_amdgcn_s_setprio(1); \
    MFOPS; \
    __builtin_amdgcn_s_setprio(0); \
    SB0; \
} while (0)

#define ITER8(LDKC, kt0_, SG2, SG3, SG4, SG5, SG6, SG7, SG8, E4, E8) \
    PH(DSA2(0,0); DSB2(0,0,bq0); LGK8, STGA(LDKC,1,1,(kt0_)+1), QMF(0,0,bq0), ); \
    PH(DSB2(0,1,bq1),            SG2,                     QMF(0,1,bq1), ); \
    PH(DSA2(0,1),                SG3,                     QMF(1,0,bq0), ); \
    PH(,                         SG4,                     QMF(1,1,bq1), E4); \
    PH(DSA2(1,0); DSB2(1,0,bq0); LGK8, SG5,               QMF(0,0,bq0), ); \
    PH(DSB2(1,1,bq1),            SG6,                     QMF(0,1,bq1), ); \
    PH(DSA2(1,1),                SG7,                     QMF(1,0,bq0), ); \
    PH(,                         SG8,                     QMF(1,1,bq1), E8);

#define GEMM_PIPE(LDKC, NI_) \
    short8 a[4][2], bq0[2][2], bq1[2][2]; \
    f32x4 acc[2][2][4][2]; \
    _Pragma("unroll") for (int q_ = 0; q_ < 2; ++q_) \
    _Pragma("unroll") for (int r_ = 0; r_ < 2; ++r_) \
    _Pragma("unroll") for (int m_ = 0; m_ < 4; ++m_) \
    _Pragma("unroll") for (int n_ = 0; n_ < 2; ++n_) acc[q_][r_][m_][n_] = (f32x4)0.0f; \
    /* prologue: slots P2..P8 -> b0.Ah0 b0.Bh0 b0.Bh1 b0.Ah1 b1.Ah0 b1.Bh0 b1.Bh1 */ \
    STGA(LDKC,0,0,0); STGB(LDKC,0,0,0); STGB(LDKC,0,1,0); STGA(LDKC,0,1,0); \
    STGA(LDKC,1,0,1); STGB(LDKC,1,0,1); STGB(LDKC,1,1,1); \
    VMC(6); \
    __builtin_amdgcn_s_barrier(); \
    for (int it = 0; it < (NI_) - 1; ++it) { \
        const int kt0 = 2 * it; \
        ITER8(LDKC, kt0, \
              STGA(LDKC,0,0,kt0+2), STGB(LDKC,0,0,kt0+2), STGB(LDKC,0,1,kt0+2), STGA(LDKC,0,1,kt0+2), \
              STGA(LDKC,1,0,kt0+3), STGB(LDKC,1,0,kt0+3), STGB(LDKC,1,1,kt0+3), \
              VMC(6), VMC(6)) \
    } \
    { \
        const int kt0 = 2 * ((NI_) - 1); \
        ITER8(LDKC, kt0, , , , , , , , VMC(0), ) \
    }

// ---------------- GEMM 1: x @ gate_up^T (permuted) + GEGLU, bf16 act out ----------------

__global__ __launch_bounds__(512, 2)
void gemm_gu(const unsigned short* __restrict__ A,    // x bf16 [16384][2048]
             const unsigned short* __restrict__ Bt,   // [E][2816][2048] permuted-transposed
             const float* __restrict__ probs,         // [16384]
             unsigned short* __restrict__ act) {      // [16384][1408] bf16
    __shared__ unsigned short sA[2 * 16384];
    __shared__ unsigned short sB[2 * 16384];
    GEMM_PROLOG(DIM)
    const int bid = blockIdx.x;           // 704 = 8 experts * (8 tm * 11 tn)
    const int e = bid & 7;                // expert per XCD (T1)
    const int local = bid >> 3;           // [0, 88), tm-fastest
    const int tm = local & 7;
    const int tn = local >> 3;            // [0, 11)
    const unsigned short* gA = A  + (size_t)(e * TOK_E + tm * 256) * DIM;
    const unsigned short* gB = Bt + (size_t)e * NGU * DIM + (size_t)(tn * 256) * DIM;

    GEMM_PIPE(DIM, 16)   // K = 2048 = 32 tiles of 64 = 16 iterations

    // epilogue: group g = tn*8 + qn*4 + wn; act col = g*16 + l15
    const int rgrp = lane >> 4;
    #pragma unroll
    for (int qm = 0; qm < 2; ++qm) {
        #pragma unroll
        for (int qn = 0; qn < 2; ++qn) {
            const int acol = tn * 128 + qn * 64 + wn * 16 + l15;
            #pragma unroll
            for (int m = 0; m < 4; ++m) {
                const int row0 = e * TOK_E + tm * 256 + qm * 128 + wm * 64 + m * 16 + rgrp * 4;
                #pragma unroll
                for (int j = 0; j < 4; ++j) {
                    float p = probs[row0 + j];
                    float g = fminf(acc[qm][qn][m][0][j], 7.0f);
                    float u = fminf(fmaxf(acc[qm][qn][m][1][j], -7.0f), 7.0f);
                    float glu = g / (1.0f + __expf(-1.702f * g));
                    float r = glu * (u + 1.0f) * p;
                    act[(size_t)(row0 + j) * INTER + acol] = f2bf(r);
                }
            }
        }
    }
}

// ---------------- GEMM 2: act @ down^T, fp32 out ----------------

__global__ __launch_bounds__(512, 2)
void gemm_down(const unsigned short* __restrict__ A,   // act bf16 [16384][1408]
               const unsigned short* __restrict__ Bt,  // [E][2048][1408]
               float* __restrict__ out) {               // [16384][2048] fp32
    __shared__ unsigned short sA[2 * 16384];
    __shared__ unsigned short sB[2 * 16384];
    GEMM_PROLOG(INTER)
    const int bid = blockIdx.x;           // 512 = 8 experts * (8 tm * 8 tn)
    const int e = bid & 7;
    const int local = bid >> 3;           // [0, 64), tm-fastest
    const int tm = local & 7;
    const int tn = local >> 3;            // [0, 8)
    const unsigned short* gA = A  + (size_t)(e * TOK_E + tm * 256) * INTER;
    const unsigned short* gB = Bt + (size_t)e * DIM * INTER + (size_t)(tn * 256) * INTER;

    GEMM_PIPE(INTER, 11)   // K = 1408 = 22 tiles of 64 = 11 iterations

    const int rgrp = lane >> 4;
    #pragma unroll
    for (int qm = 0; qm < 2; ++qm) {
        #pragma unroll
        for (int qn = 0; qn < 2; ++qn) {
            #pragma unroll
            for (int m = 0; m < 4; ++m) {
                const int row0 = e * TOK_E + tm * 256 + qm * 128 + wm * 64 + m * 16 + rgrp * 4;
                #pragma unroll
                for (int j = 0; j < 4; ++j) {
                    #pragma unroll
                    for (int n = 0; n < 2; ++n) {
                        const int col = tn * 256 + qn * 128 + wn * 32 + n * 16 + l15;
                        out[(size_t)(row0 + j) * DIM + col] = acc[qm][qn][m][n][j];
                    }
                }
            }
        }
    }
}

// ---------------- launcher ----------------

extern "C" void kernel_launch(void* const* d_in, const int* in_sizes, int n_in,
                              void* d_out, int out_size, void* d_ws, size_t ws_size,
                              hipStream_t stream) {
    const float* x     = (const float*)d_in[0];
    const float* probs = (const float*)d_in[1];
    const float* gup   = (const float*)d_in[2];
    const float* dwn   = (const float*)d_in[3];
    float* out = (float*)d_out;

    char* ws = (char*)d_ws;
    const size_t SZ_XB  = (size_t)TOTAL_TOKENS * DIM * 2;      // 67,108,864
    const size_t SZ_GUB = (size_t)N_EXPERTS * NGU * DIM * 2;   // 92,274,688
    const size_t SZ_DWB = (size_t)N_EXPERTS * DIM * INTER * 2; // 46,137,344
    unsigned short* xb   = (unsigned short*)(ws);
    unsigned short* gub  = (unsigned short*)(ws + SZ_XB);
    unsigned short* dwb  = (unsigned short*)(ws + SZ_XB + SZ_GUB);
    unsigned short* actb = (unsigned short*)(ws + SZ_XB + SZ_GUB + SZ_DWB);

    convert_x<<<2048, 256, 0, stream>>>(x, xb, TOTAL_TOKENS * DIM / 8);

    dim3 tg1(NGU / 32, DIM / 128, N_EXPERTS);     // (88, 16, 8)
    transpose_convert<<<tg1, 256, 0, stream>>>(gup, gub, DIM, NGU, 1);
    dim3 tg2(DIM / 32, INTER / 128, N_EXPERTS);   // (64, 11, 8)
    transpose_convert<<<tg2, 256, 0, stream>>>(dwn, dwb, INTER, DIM, 0);

    gemm_gu<<<704, 512, 0, stream>>>(xb, gub, probs, actb);
    gemm_down<<<512, 512, 0, stream>>>(actb, dwb, out);
}